// Round 6
// baseline (1059.961 us; speedup 1.0000x reference)
//
#include <hip/hip_runtime.h>
#include <hip/hip_bf16.h>
#include <math.h>

#define BATCH 8
#define CH 48
#define HH 256
#define WW 256
#define NPROMPT 16
#define NEXP 8
#define NGRP 4
#define GDIM 12
#define HW (HH * WW)

// MFMA A-fragment tables: [tap(9)][mtile(3)][kblock(2)][lane(64)][j(8)] bf16
#define FRAG_ELEMS (9 * 3 * 2 * 64 * 8)   // 27648 elems = 55296 B per (image|expert)
#define FRAG_BYTES (FRAG_ELEMS * 2)

typedef short bf16x8 __attribute__((ext_vector_type(8)));   // 8 bf16 (4 VGPRs)
typedef float f32x4  __attribute__((ext_vector_type(4)));
typedef unsigned short u16x4 __attribute__((ext_vector_type(4)));

// 16x8 output tile (was 16x16): staged LDS 23.5 KB -> 6 blocks/CU resident
// (was 41 KB -> 2.5 blocks/CU, OccupancyPercent 27%, the R5 latency wall).
#define TILE_W 16
#define TILE_H 8
#define ITILE_W 18                  // staged cols
#define ITILE_H 10                  // staged rows
#define NPIX (ITILE_W * ITILE_H)    // 180
#define PIXB 128                    // LDS bytes/pixel (8 slots x 16B, swizzled)
#define ROWB (ITILE_W * PIXB)       // 2304 B per staged row
#define STAGE_K 23                  // DMA chunks of 64 x 16B (1440 items + pad)
#define LDSBYTES (STAGE_K * 1024)   // 23552
#define GPIXB 96                    // global NHWC-48 bf16 bytes/pixel
#define IMGB ((size_t)HW * GPIXB)   // 6291456 B per image
#define NTILES 512                  // (256/TILE_W)*(256/TILE_H)

__device__ __forceinline__ unsigned short f2bf(float f) {
    unsigned u = __float_as_uint(f);
    unsigned r = (u + 0x7FFFu + ((u >> 16) & 1u)) >> 16;   // RNE
    return (unsigned short)r;
}

// async global->LDS DMA, 16B per lane; lds dest = uniform base + lane*16
__device__ __forceinline__ void load_lds16(const void* g, void* l) {
    __builtin_amdgcn_global_load_lds(
        (const __attribute__((address_space(1))) unsigned int*)g,
        (__attribute__((address_space(3))) unsigned int*)l, 16, 0, 0);
}

// ---------------------------------------------------------------------------
// Kernel 1: fold branch-a + branch-b into per-image 3x3 weights in MFMA
// A-fragment layout. Also zero the DMA zero-page.
// ---------------------------------------------------------------------------
__global__ __launch_bounds__(256) void precompute_kernel(
    const float* __restrict__ P_hat,
    const float* __restrict__ proj_a_w,
    const float* __restrict__ proj_b_w,
    const float* __restrict__ dw_b_w,
    const float* __restrict__ fi_align_w,
    unsigned short* __restrict__ wfxf,
    float* __restrict__ zpage)
{
    int b = blockIdx.x;
    int tid = threadIdx.x;
    __shared__ float p_avg[CH];
    __shared__ float W_fi[NGRP * CH];
    __shared__ float W_a[CH * CH];

    if (tid < CH) {
        float s = 0.f;
        for (int n = 0; n < NPROMPT; n++)
            s += P_hat[(b * NPROMPT + n) * CH + tid];
        p_avg[tid] = s * (1.0f / NPROMPT);
    }
    if (b == 0 && tid < 64) zpage[tid] = 0.f;   // 256 B zero page
    __syncthreads();

    if (tid < NGRP * CH) {
        int g = tid / CH, k = tid % CH;
        float s = 0.f;
        for (int j = 0; j < GDIM; j++) {
            int c = g * GDIM + j;
            s += p_avg[c] * proj_a_w[c * CH + k];
        }
        W_fi[tid] = s;
    }
    __syncthreads();

    for (int e = tid; e < CH * CH; e += 256) {
        int o = e / CH, k = e % CH;
        float s = 0.f;
        for (int g = 0; g < NGRP; g++)
            s += fi_align_w[o * NGRP + g] * W_fi[g * CH + k];
        W_a[e] = s;
    }
    __syncthreads();

    for (int i = tid; i < FRAG_ELEMS; i += 256) {
        int j = i & 7;
        int lane = (i >> 3) & 63;
        int blk = i >> 9;            // (tap*3+mt)*2+kb
        int kb = blk & 1;
        int tmp = blk >> 1;
        int mt = tmp % 3, tap = tmp / 3;
        int oc = mt * 16 + (lane & 15);
        int cin = kb * 32 + (lane >> 4) * 8 + j;
        float v = 0.f;
        if (cin < CH) {
            v = dw_b_w[oc * 9 + tap] * proj_b_w[oc * CH + cin];
            if (tap == 4) v += W_a[oc * CH + cin];
        }
        wfxf[(size_t)b * FRAG_ELEMS + i] = f2bf(v);
    }
}

// ---------------------------------------------------------------------------
// Kernel 2: repack expert weights into MFMA A-fragment layout.
// ---------------------------------------------------------------------------
__global__ __launch_bounds__(256) void repack_kernel(
    const float* __restrict__ w1, const float* __restrict__ w2,
    unsigned short* __restrict__ w1f, unsigned short* __restrict__ w2f)
{
    int e = blockIdx.x;
    const float* src = blockIdx.y ? w2 : w1;
    unsigned short* dst = blockIdx.y ? w2f : w1f;
    for (int i = threadIdx.x; i < FRAG_ELEMS; i += 256) {
        int j = i & 7;
        int lane = (i >> 3) & 63;
        int blk = i >> 9;
        int kb = blk & 1;
        int tmp = blk >> 1;
        int mt = tmp % 3, tap = tmp / 3;
        int oc = mt * 16 + (lane & 15);
        int cin = kb * 32 + (lane >> 4) * 8 + j;
        float v = (cin < CH) ? src[(((size_t)e * CH + oc) * CH + cin) * 9 + tap] : 0.f;
        dst[(size_t)e * FRAG_ELEMS + i] = f2bf(v);
    }
}

// ---------------------------------------------------------------------------
// Kernel 3: transpose x NCHW fp32 -> dense NHWC-48 bf16 (96 B/pixel).
// ---------------------------------------------------------------------------
__global__ __launch_bounds__(256) void transpose_kernel(
    const float* __restrict__ x, unsigned short* __restrict__ xT)
{
    __shared__ float t[CH * 65];
    int pix0 = blockIdx.x * 64;
    int b = pix0 >> 16;
    int rem = pix0 & 65535;
    int tid = threadIdx.x;
    int px = tid & 63, c0 = tid >> 6;

    float v[12];
#pragma unroll
    for (int k = 0; k < 12; k++)
        v[k] = x[(((size_t)(b * CH + c0 + 4 * k)) << 16) + rem + px];
#pragma unroll
    for (int k = 0; k < 12; k++)
        t[(c0 + 4 * k) * 65 + px] = v[k];
    __syncthreads();

#pragma unroll
    for (int k = 0; k < 2; k++) {
        int w = tid + 256 * k;
        if (w < 384) {
            int p2 = w / 6, o = w % 6;
            bf16x8 pk;
#pragma unroll
            for (int j = 0; j < 8; j++)
                pk[j] = (short)f2bf(t[(o * 8 + j) * 65 + p2]);
            *(bf16x8*)((char*)xT + (size_t)pix0 * GPIXB + (size_t)w * 16) = pk;
        }
    }
}

// ---------------------------------------------------------------------------
// Block-cooperative DMA staging: LDS[p][slot] (PIXB=128) <- global dense
// NHWC-48 (96B/pixel).  LDS slot o of pixel p holds channel-octet
// m = o ^ (gx&7) (swizzle in LDS only -> conflict-free ds_read_b128).
// OOB pixels / pad octets <- zero page.  Caller must __syncthreads() after.
// 10x18 staged region, 1440 16-B items (+32 pad -> STAGE_K*64).
// ---------------------------------------------------------------------------
__device__ __forceinline__ void stage_swz(
    const char* __restrict__ srcimg, int oy0, int ox0,
    char* smem, const char* __restrict__ zp)
{
    int wv = threadIdx.x >> 6, lane = threadIdx.x & 63;
    for (int k = wv; k < STAGE_K; k += 4) {
        int w = k * 64 + lane;
        int px = w >> 3, o = w & 7;
        int yy = px / ITILE_W, xx = px - yy * ITILE_W;
        int gy = oy0 + yy - 1, gx = ox0 + xx - 1;
        int m = o ^ (gx & 7);
        const char* g = zp;
        if (px < NPIX && (unsigned)gy < 256u && (unsigned)gx < 256u && m < 6)
            g = srcimg + (size_t)((gy << 8) + gx) * GPIXB + m * 16;
        load_lds16(g, smem + k * 1024);
    }
}

// ---------------------------------------------------------------------------
// Core: 9-tap K=64 MFMA GEMM. M=48 (3 mtiles), N=16 px/row, 2 rows per wave.
// A-frags double-buffered across taps; B reads swizzle-indexed (2-way free).
// SWAP=true -> C[pix][oc] for float4 NCHW epilogue (conv2).
// ---------------------------------------------------------------------------
template <bool ACC, bool SWAP>
__device__ __forceinline__ void conv_core(
    const char* smem, const unsigned short* __restrict__ wfrag,
    int ox0, f32x4 acc[2][3])
{
    const int lane = threadIdx.x & 63;
    const int wv = threadIdx.x >> 6;
    const int n = lane & 15;
    const int quad = lane >> 4;
    const bf16x8* wp = (const bf16x8*)wfrag;

    if (!ACC) {
#pragma unroll
        for (int g = 0; g < 2; ++g)
#pragma unroll
            for (int mt = 0; mt < 3; ++mt)
                acc[g][mt] = (f32x4){0.f, 0.f, 0.f, 0.f};
    }

    // per-dx lane-dependent column offsets (kb0 and kb1 slots)
    int colb0[3], colb1[3];
#pragma unroll
    for (int dx = 0; dx < 3; ++dx) {
        int key = (ox0 - 1 + dx + n) & 7;
        colb0[dx] = (dx + n) * PIXB + ((quad ^ key) * 16);
        colb1[dx] = (dx + n) * PIXB + (((quad + 4) ^ key) * 16);
    }

    bf16x8 a[2][6];
#pragma unroll
    for (int mt = 0; mt < 3; ++mt) {
        a[0][mt]     = wp[(mt * 2 + 0) * 64 + lane];
        a[0][mt + 3] = wp[(mt * 2 + 1) * 64 + lane];
    }

#pragma unroll
    for (int tap = 0; tap < 9; ++tap) {
        const int cur = tap & 1;
        if (tap < 8) {
#pragma unroll
            for (int mt = 0; mt < 3; ++mt) {
                a[cur ^ 1][mt]     = wp[(((tap + 1) * 3 + mt) * 2 + 0) * 64 + lane];
                a[cur ^ 1][mt + 3] = wp[(((tap + 1) * 3 + mt) * 2 + 1) * 64 + lane];
            }
        }
        const int dy = tap / 3, dx = tap % 3;
#pragma unroll
        for (int g = 0; g < 2; ++g) {
            const int rowb = (wv * 2 + g + dy) * ROWB;
            bf16x8 b0 = *(const bf16x8*)(smem + rowb + colb0[dx]);
            bf16x8 b1 = *(const bf16x8*)(smem + rowb + colb1[dx]);
            if (SWAP) {
                acc[g][0] = __builtin_amdgcn_mfma_f32_16x16x32_bf16(b0, a[cur][0], acc[g][0], 0, 0, 0);
                acc[g][1] = __builtin_amdgcn_mfma_f32_16x16x32_bf16(b0, a[cur][1], acc[g][1], 0, 0, 0);
                acc[g][2] = __builtin_amdgcn_mfma_f32_16x16x32_bf16(b0, a[cur][2], acc[g][2], 0, 0, 0);
                acc[g][0] = __builtin_amdgcn_mfma_f32_16x16x32_bf16(b1, a[cur][3], acc[g][0], 0, 0, 0);
                acc[g][1] = __builtin_amdgcn_mfma_f32_16x16x32_bf16(b1, a[cur][4], acc[g][1], 0, 0, 0);
                acc[g][2] = __builtin_amdgcn_mfma_f32_16x16x32_bf16(b1, a[cur][5], acc[g][2], 0, 0, 0);
            } else {
                acc[g][0] = __builtin_amdgcn_mfma_f32_16x16x32_bf16(a[cur][0], b0, acc[g][0], 0, 0, 0);
                acc[g][1] = __builtin_amdgcn_mfma_f32_16x16x32_bf16(a[cur][1], b0, acc[g][1], 0, 0, 0);
                acc[g][2] = __builtin_amdgcn_mfma_f32_16x16x32_bf16(a[cur][2], b0, acc[g][2], 0, 0, 0);
                acc[g][0] = __builtin_amdgcn_mfma_f32_16x16x32_bf16(a[cur][3], b1, acc[g][0], 0, 0, 0);
                acc[g][1] = __builtin_amdgcn_mfma_f32_16x16x32_bf16(a[cur][4], b1, acc[g][1], 0, 0, 0);
                acc[g][2] = __builtin_amdgcn_mfma_f32_16x16x32_bf16(a[cur][5], b1, acc[g][2], 0, 0, 0);
            }
        }
    }
}

// dense NHWC-48 bf16 store of one conv result (oc channels of pixel col n)
__device__ __forceinline__ void store_pix(
    char* __restrict__ dstimg, int row, int col, int quad,
    const f32x4 v[3])
{
    size_t pb = (size_t)((row << 8) + col) * GPIXB;
#pragma unroll
    for (int mt = 0; mt < 3; ++mt) {
        u16x4 pk;
#pragma unroll
        for (int r = 0; r < 4; ++r) pk[r] = f2bf(v[mt][r]);
        *(u16x4*)(dstimg + pb + mt * 32 + quad * 8) = pk;
    }
}

// ---------------------------------------------------------------------------
// Kernel 4: Fx = conv3x3(xT, Wfx[b]) -> dense NHWC bf16, + fused GAP partials.
// ---------------------------------------------------------------------------
__global__ __launch_bounds__(256, 6) void fxconv_kernel(
    const unsigned short* __restrict__ xT, const unsigned short* __restrict__ wfxf,
    unsigned short* __restrict__ Fx, float* __restrict__ gapP,
    const float* __restrict__ zp)
{
    __shared__ __align__(16) char smem[LDSBYTES];
    int ox0 = blockIdx.x * TILE_W, oy0 = blockIdx.y * TILE_H, b = blockIdx.z;

    stage_swz((const char*)xT + (size_t)b * IMGB, oy0, ox0, smem, (const char*)zp);
    __syncthreads();

    f32x4 acc[2][3];
    conv_core<false, false>(smem, wfxf + (size_t)b * FRAG_ELEMS, ox0, acc);

    const int lane = threadIdx.x & 63;
    const int wv = threadIdx.x >> 6;
    const int n = lane & 15, quad = lane >> 4;
    char* dimg = (char*)Fx + (size_t)b * IMGB;

    float gsum[3][4];
#pragma unroll
    for (int mt = 0; mt < 3; ++mt)
#pragma unroll
        for (int r = 0; r < 4; ++r) gsum[mt][r] = 0.f;

#pragma unroll
    for (int g = 0; g < 2; ++g) {
        int row = oy0 + wv * 2 + g;
        store_pix(dimg, row, ox0 + n, quad, acc[g]);
#pragma unroll
        for (int mt = 0; mt < 3; ++mt)
#pragma unroll
            for (int r = 0; r < 4; ++r) gsum[mt][r] += acc[g][mt][r];
    }
    // reduce over the 16 pixel columns (n bits = lane bits 0..3)
#pragma unroll
    for (int mt = 0; mt < 3; ++mt)
#pragma unroll
        for (int r = 0; r < 4; ++r) {
            float v = gsum[mt][r];
            v += __shfl_xor(v, 1);
            v += __shfl_xor(v, 2);
            v += __shfl_xor(v, 4);
            v += __shfl_xor(v, 8);
            gsum[mt][r] = v;
        }

    // cross-wave reduce in LDS (smem free after conv_core by all waves)
    __syncthreads();
    float* smemf = (float*)smem;
    if (n == 0) {
#pragma unroll
        for (int mt = 0; mt < 3; ++mt)
#pragma unroll
            for (int r = 0; r < 4; ++r)
                smemf[wv * CH + mt * 16 + quad * 4 + r] = gsum[mt][r];
    }
    __syncthreads();
    int t = threadIdx.x;
    if (t < CH) {
        float v = smemf[t] + smemf[CH + t] + smemf[2 * CH + t] + smemf[3 * CH + t];
        int tile = blockIdx.y * 16 + blockIdx.x;   // [0, NTILES)
        gapP[((size_t)b * NTILES + tile) * CH + t] = v;
    }
}

// ---------------------------------------------------------------------------
// Kernel 5: routing. One block per image: reduce NTILES per-tile GAP
// partials (thread t owns tiles t and t+256), then linear + top-2 gate.
// ---------------------------------------------------------------------------
__global__ __launch_bounds__(256) void route_kernel(
    const float* __restrict__ gapP,
    const float* __restrict__ router_w,
    const float* __restrict__ router_b,
    float* __restrict__ gate, int* __restrict__ eidx)
{
    __shared__ float red4[4 * CH];
    __shared__ float scs[NEXP];
    int b = blockIdx.x, t = threadIdx.x;
    int lane = t & 63, wv = t >> 6;

    const float* s1 = gapP + ((size_t)b * NTILES + t) * CH;
    const float* s2 = s1 + 256 * CH;
    float s[CH];
#pragma unroll
    for (int c = 0; c < CH; c++) s[c] = s1[c] + s2[c];
#pragma unroll
    for (int c = 0; c < CH; c++) {
        float v = s[c];
        v += __shfl_xor(v, 1);
        v += __shfl_xor(v, 2);
        v += __shfl_xor(v, 4);
        v += __shfl_xor(v, 8);
        v += __shfl_xor(v, 16);
        v += __shfl_xor(v, 32);
        if (lane == 0) red4[wv * CH + c] = v;
    }
    __syncthreads();

    if (t < NEXP) {
        float sc = router_b[t];
        for (int c = 0; c < CH; c++) {
            float g = (red4[c] + red4[CH + c] + red4[2 * CH + c] + red4[3 * CH + c])
                      * (1.0f / HW);
            sc += g * router_w[t * CH + c];
        }
        scs[t] = sc;
    }
    __syncthreads();

    if (t == 0) {
        float v0 = -1e30f, v1 = -1e30f;
        int i0 = 0, i1 = 0;
        for (int e = 0; e < NEXP; e++) {
            float se = scs[e];
            if (se > v0) { v1 = v0; i1 = i0; v0 = se; i0 = e; }
            else if (se > v1) { v1 = se; i1 = e; }
        }
        float ex = expf(v1 - v0);
        float dn = 1.0f / (1.0f + ex);
        gate[b * 2 + 0] = dn;
        gate[b * 2 + 1] = ex * dn;
        eidx[b * 2 + 0] = i0;
        eidx[b * 2 + 1] = i1;
    }
}

// ---------------------------------------------------------------------------
// Kernel 6: w2s[b][slot] = gate[b][slot] * w2f[eidx[b][slot]]  (A-frag bf16).
// ---------------------------------------------------------------------------
__global__ __launch_bounds__(256) void scale_kernel(
    const unsigned short* __restrict__ w2f, const float* __restrict__ gate,
    const int* __restrict__ eidx, unsigned short* __restrict__ w2s)
{
    int b = blockIdx.x, s = blockIdx.y;
    int e = eidx[b * 2 + s];
    float g = gate[b * 2 + s];
    const unsigned short* src = w2f + (size_t)e * FRAG_ELEMS;
    unsigned short* dst = w2s + (size_t)(b * 2 + s) * FRAG_ELEMS;
    for (int i = threadIdx.x; i < FRAG_ELEMS; i += 256) {
        float v = __uint_as_float((unsigned)src[i] << 16);
        dst[i] = f2bf(v * g);
    }
}

// ---------------------------------------------------------------------------
// Kernel 7: both routed experts' conv1 from ONE staged Fx tile:
//   hmid_s = gelu(conv3x3(Fx, w1[e_s])), s = 0,1.
// ---------------------------------------------------------------------------
__global__ __launch_bounds__(256, 6) void conv1_both_kernel(
    const unsigned short* __restrict__ Fx, const unsigned short* __restrict__ w1f,
    const int* __restrict__ eidx, const float* __restrict__ zp,
    unsigned short* __restrict__ hmid0, unsigned short* __restrict__ hmid1)
{
    __shared__ __align__(16) char smem[LDSBYTES];
    int ox0 = blockIdx.x * TILE_W, oy0 = blockIdx.y * TILE_H, b = blockIdx.z;

    stage_swz((const char*)Fx + (size_t)b * IMGB, oy0, ox0, smem, (const char*)zp);
    __syncthreads();

    const int lane = threadIdx.x & 63;
    const int wv = threadIdx.x >> 6;
    const int n = lane & 15, quad = lane >> 4;

    f32x4 acc[2][3];
#pragma unroll
    for (int s = 0; s < 2; ++s) {
        int e = __builtin_amdgcn_readfirstlane(eidx[b * 2 + s]);
        conv_core<false, false>(smem, w1f + (size_t)e * FRAG_ELEMS, ox0, acc);
        char* dimg = (char*)(s ? hmid1 : hmid0) + (size_t)b * IMGB;
#pragma unroll
        for (int g = 0; g < 2; ++g) {
            int row = oy0 + wv * 2 + g;
            f32x4 h[3];
#pragma unroll
            for (int mt = 0; mt < 3; ++mt)
#pragma unroll
                for (int r = 0; r < 4; ++r) {
                    float a = acc[g][mt][r];
                    h[mt][r] = 0.5f * a * (1.0f + erff(a * 0.70710678118654752f));
                }
            store_pix(dimg, row, ox0 + n, quad, h);
        }
    }
}

// ---------------------------------------------------------------------------
// Kernel 8: out = x + conv3x3(hmid0, g0*w2[e0]) + conv3x3(hmid1, g1*w2[e1]).
// SWAPped MFMA -> C[pix][oc]: float4 NCHW residual/stores.  Pair-XCD
// swizzle keeps the two tiles sharing each 128-B out line on one XCD.
// ---------------------------------------------------------------------------
__global__ __launch_bounds__(256, 6) void conv2_both_kernel(
    const unsigned short* __restrict__ hmid0, const unsigned short* __restrict__ hmid1,
    const unsigned short* __restrict__ w2s, const float* __restrict__ zp,
    const float* __restrict__ x, float* __restrict__ out)
{
    __shared__ __align__(16) char smem[LDSBYTES];
    // d = rest*16 + half*8 + k8 -> bx = 2*k8+half, (by,b) = rest  (bijective)
    int d = blockIdx.x;
    int k8   = d & 7;
    int half = (d >> 3) & 1;
    int rest = d >> 4;             // [0, 256)
    int bx = k8 * 2 + half;        // [0, 16)
    int by = rest & 31;            // [0, 32)
    int b  = rest >> 5;            // [0, 8)
    int ox0 = bx * TILE_W, oy0 = by * TILE_H;

    const int lane = threadIdx.x & 63;
    const int wv = threadIdx.x >> 6;
    const int n = lane & 15, quad = lane >> 4;

    // residual prefetch: 6 float4/lane (pixels quad*4..+3 of oc nt*16+n)
    f32x4 xr[2][3];
#pragma unroll
    for (int g = 0; g < 2; ++g) {
        int row = oy0 + wv * 2 + g;
#pragma unroll
        for (int nt = 0; nt < 3; ++nt) {
            int oc = nt * 16 + n;
            size_t idx = (((size_t)b * CH + oc) << 16) + (row << 8) + ox0 + quad * 4;
            xr[g][nt] = *(const f32x4*)(x + idx);
        }
    }

    f32x4 acc[2][3];

    stage_swz((const char*)hmid0 + (size_t)b * IMGB, oy0, ox0, smem, (const char*)zp);
    __syncthreads();
    conv_core<false, true>(smem, w2s + (size_t)(b * 2 + 0) * FRAG_ELEMS, ox0, acc);
    __syncthreads();   // all waves done reading before re-stage

    stage_swz((const char*)hmid1 + (size_t)b * IMGB, oy0, ox0, smem, (const char*)zp);
    __syncthreads();
    conv_core<true, true>(smem, w2s + (size_t)(b * 2 + 1) * FRAG_ELEMS, ox0, acc);

#pragma unroll
    for (int g = 0; g < 2; ++g) {
        int row = oy0 + wv * 2 + g;
#pragma unroll
        for (int nt = 0; nt < 3; ++nt) {
            int oc = nt * 16 + n;
            size_t idx = (((size_t)b * CH + oc) << 16) + (row << 8) + ox0 + quad * 4;
            *(f32x4*)(out + idx) = xr[g][nt] + acc[g][nt];
        }
    }
}

// ---------------------------------------------------------------------------
extern "C" void kernel_launch(void* const* d_in, const int* in_sizes, int n_in,
                              void* d_out, int out_size, void* d_ws, size_t ws_size,
                              hipStream_t stream) {
    (void)in_sizes; (void)n_in; (void)out_size; (void)ws_size;
    const float* x          = (const float*)d_in[0];
    const float* P_hat      = (const float*)d_in[1];
    const float* proj_a_w   = (const float*)d_in[2];
    const float* proj_b_w   = (const float*)d_in[3];
    const float* dw_b_w     = (const float*)d_in[4];
    const float* fi_align_w = (const float*)d_in[5];
    const float* expert_w1  = (const float*)d_in[6];
    const float* expert_w2  = (const float*)d_in[7];
    const float* router_w   = (const float*)d_in[8];
    const float* router_b   = (const float*)d_in[9];
    float* out = (float*)d_out;

    // d_out doubles as scratch before the final conv2 pass overwrites it:
    //   [0, 50331648)          Fx (bf16 NHWC-48)
    //   [62914560, +1327104)   wfxf / w1f / w2f fragment tables
    //   [64241664, +786432)    gapP per-tile GAP partials (consumed by route)
    char* ob = (char*)d_out;
    unsigned short* Fx   = (unsigned short*)ob;
    unsigned short* wfxf = (unsigned short*)(ob + 62914560);
    unsigned short* w1f  = (unsigned short*)(ob + 62914560 + FRAG_BYTES * NEXP);
    unsigned short* w2f  = (unsigned short*)(ob + 62914560 + 2 * FRAG_BYTES * NEXP);
    float*          gapP = (float*)(ob + 64241664);

    // ws: xT (aliased by hmid1 after fxconv) | hmid0 | w2s | zpage | gate | eidx
    char* ws = (char*)d_ws;
    unsigned short* xT    = (unsigned short*)ws;               // 50331648 B
    unsigned short* hmid1 = (unsigned short*)ws;               // alias (xT dead)
    unsigned short* hmid0 = (unsigned short*)(ws + 50331648);  // 50331648 B
    unsigned short* w2s   = (unsigned short*)(ws + 100663296); // 884736 B
    float* zp   = (float*)(ws + 100663296 + 884736);           // 256 B
    float* gate = (float*)(ws + 100663296 + 884736 + 256 + 1536); // 64 B
    int*   eidx = (int*)(gate + BATCH * 2);                    // 64 B

    precompute_kernel<<<dim3(BATCH), 256, 0, stream>>>(
        P_hat, proj_a_w, proj_b_w, dw_b_w, fi_align_w, wfxf, zp);

    repack_kernel<<<dim3(NEXP, 2), 256, 0, stream>>>(
        expert_w1, expert_w2, w1f, w2f);

    transpose_kernel<<<dim3(BATCH * HW / 64), 256, 0, stream>>>(x, xT);

    fxconv_kernel<<<dim3(16, 32, BATCH), 256, 0, stream>>>(xT, wfxf, Fx, gapP, zp);

    route_kernel<<<dim3(BATCH), 256, 0, stream>>>(gapP, router_w, router_b, gate, eidx);

    scale_kernel<<<dim3(BATCH, 2), 256, 0, stream>>>(w2f, gate, eidx, w2s);

    conv1_both_kernel<<<dim3(16, 32, BATCH), 256, 0, stream>>>(
        Fx, w1f, eidx, zp, hmid0, hmid1);

    conv2_both_kernel<<<dim3(4096), 256, 0, stream>>>(
        hmid0, hmid1, w2s, zp, x, out);
}

// Round 7
// 569.460 us; speedup vs baseline: 1.8613x; 1.8613x over previous
//
#include <hip/hip_runtime.h>
#include <hip/hip_bf16.h>
#include <math.h>

#define BATCH 8
#define CH 48
#define HH 256
#define WW 256
#define NPROMPT 16
#define NEXP 8
#define NGRP 4
#define GDIM 12
#define HW (HH * WW)

// MFMA A-fragment tables: [tap(9)][mtile(3)][kblock(2)][lane(64)][j(8)] bf16
#define FRAG_ELEMS (9 * 3 * 2 * 64 * 8)   // 27648 elems = 55296 B per (image|expert)
#define FRAG_BYTES (FRAG_ELEMS * 2)

typedef short bf16x8 __attribute__((ext_vector_type(8)));   // 8 bf16 (4 VGPRs)
typedef float f32x4  __attribute__((ext_vector_type(4)));
typedef unsigned short u16x4 __attribute__((ext_vector_type(4)));

// 16x8 output tile: staged LDS 23.5 KB.  R6 lesson: pairing this with
// __launch_bounds__(256,6) capped VGPRs at ~85 and the allocator collapsed
// to 40 -> massive scratch spills (FETCH 494 MB, WRITE 1088 MB, 536 us).
// (256,4) gives a 128-VGPR cap (>= ~96 natural usage, zero spills) and
// 4 blocks/CU = 50% occupancy (vs R5's 27%).
#define TILE_W 16
#define TILE_H 8
#define ITILE_W 18                  // staged cols
#define ITILE_H 10                  // staged rows
#define NPIX (ITILE_W * ITILE_H)    // 180
#define PIXB 128                    // LDS bytes/pixel (8 slots x 16B, swizzled)
#define ROWB (ITILE_W * PIXB)       // 2304 B per staged row
#define STAGE_K 23                  // DMA chunks of 64 x 16B (1440 items + pad)
#define LDSBYTES (STAGE_K * 1024)   // 23552
#define GPIXB 96                    // global NHWC-48 bf16 bytes/pixel
#define IMGB ((size_t)HW * GPIXB)   // 6291456 B per image
#define NTILES 512                  // (256/TILE_W)*(256/TILE_H)

__device__ __forceinline__ unsigned short f2bf(float f) {
    unsigned u = __float_as_uint(f);
    unsigned r = (u + 0x7FFFu + ((u >> 16) & 1u)) >> 16;   // RNE
    return (unsigned short)r;
}

// async global->LDS DMA, 16B per lane; lds dest = uniform base + lane*16
__device__ __forceinline__ void load_lds16(const void* g, void* l) {
    __builtin_amdgcn_global_load_lds(
        (const __attribute__((address_space(1))) unsigned int*)g,
        (__attribute__((address_space(3))) unsigned int*)l, 16, 0, 0);
}

// ---------------------------------------------------------------------------
// Kernel 1: fold branch-a + branch-b into per-image 3x3 weights in MFMA
// A-fragment layout. Also zero the DMA zero-page.
// ---------------------------------------------------------------------------
__global__ __launch_bounds__(256) void precompute_kernel(
    const float* __restrict__ P_hat,
    const float* __restrict__ proj_a_w,
    const float* __restrict__ proj_b_w,
    const float* __restrict__ dw_b_w,
    const float* __restrict__ fi_align_w,
    unsigned short* __restrict__ wfxf,
    float* __restrict__ zpage)
{
    int b = blockIdx.x;
    int tid = threadIdx.x;
    __shared__ float p_avg[CH];
    __shared__ float W_fi[NGRP * CH];
    __shared__ float W_a[CH * CH];

    if (tid < CH) {
        float s = 0.f;
        for (int n = 0; n < NPROMPT; n++)
            s += P_hat[(b * NPROMPT + n) * CH + tid];
        p_avg[tid] = s * (1.0f / NPROMPT);
    }
    if (b == 0 && tid < 64) zpage[tid] = 0.f;   // 256 B zero page
    __syncthreads();

    if (tid < NGRP * CH) {
        int g = tid / CH, k = tid % CH;
        float s = 0.f;
        for (int j = 0; j < GDIM; j++) {
            int c = g * GDIM + j;
            s += p_avg[c] * proj_a_w[c * CH + k];
        }
        W_fi[tid] = s;
    }
    __syncthreads();

    for (int e = tid; e < CH * CH; e += 256) {
        int o = e / CH, k = e % CH;
        float s = 0.f;
        for (int g = 0; g < NGRP; g++)
            s += fi_align_w[o * NGRP + g] * W_fi[g * CH + k];
        W_a[e] = s;
    }
    __syncthreads();

    for (int i = tid; i < FRAG_ELEMS; i += 256) {
        int j = i & 7;
        int lane = (i >> 3) & 63;
        int blk = i >> 9;            // (tap*3+mt)*2+kb
        int kb = blk & 1;
        int tmp = blk >> 1;
        int mt = tmp % 3, tap = tmp / 3;
        int oc = mt * 16 + (lane & 15);
        int cin = kb * 32 + (lane >> 4) * 8 + j;
        float v = 0.f;
        if (cin < CH) {
            v = dw_b_w[oc * 9 + tap] * proj_b_w[oc * CH + cin];
            if (tap == 4) v += W_a[oc * CH + cin];
        }
        wfxf[(size_t)b * FRAG_ELEMS + i] = f2bf(v);
    }
}

// ---------------------------------------------------------------------------
// Kernel 2: repack expert weights into MFMA A-fragment layout.
// ---------------------------------------------------------------------------
__global__ __launch_bounds__(256) void repack_kernel(
    const float* __restrict__ w1, const float* __restrict__ w2,
    unsigned short* __restrict__ w1f, unsigned short* __restrict__ w2f)
{
    int e = blockIdx.x;
    const float* src = blockIdx.y ? w2 : w1;
    unsigned short* dst = blockIdx.y ? w2f : w1f;
    for (int i = threadIdx.x; i < FRAG_ELEMS; i += 256) {
        int j = i & 7;
        int lane = (i >> 3) & 63;
        int blk = i >> 9;
        int kb = blk & 1;
        int tmp = blk >> 1;
        int mt = tmp % 3, tap = tmp / 3;
        int oc = mt * 16 + (lane & 15);
        int cin = kb * 32 + (lane >> 4) * 8 + j;
        float v = (cin < CH) ? src[(((size_t)e * CH + oc) * CH + cin) * 9 + tap] : 0.f;
        dst[(size_t)e * FRAG_ELEMS + i] = f2bf(v);
    }
}

// ---------------------------------------------------------------------------
// Kernel 3: transpose x NCHW fp32 -> dense NHWC-48 bf16 (96 B/pixel).
// ---------------------------------------------------------------------------
__global__ __launch_bounds__(256) void transpose_kernel(
    const float* __restrict__ x, unsigned short* __restrict__ xT)
{
    __shared__ float t[CH * 65];
    int pix0 = blockIdx.x * 64;
    int b = pix0 >> 16;
    int rem = pix0 & 65535;
    int tid = threadIdx.x;
    int px = tid & 63, c0 = tid >> 6;

    float v[12];
#pragma unroll
    for (int k = 0; k < 12; k++)
        v[k] = x[(((size_t)(b * CH + c0 + 4 * k)) << 16) + rem + px];
#pragma unroll
    for (int k = 0; k < 12; k++)
        t[(c0 + 4 * k) * 65 + px] = v[k];
    __syncthreads();

#pragma unroll
    for (int k = 0; k < 2; k++) {
        int w = tid + 256 * k;
        if (w < 384) {
            int p2 = w / 6, o = w % 6;
            bf16x8 pk;
#pragma unroll
            for (int j = 0; j < 8; j++)
                pk[j] = (short)f2bf(t[(o * 8 + j) * 65 + p2]);
            *(bf16x8*)((char*)xT + (size_t)pix0 * GPIXB + (size_t)w * 16) = pk;
        }
    }
}

// ---------------------------------------------------------------------------
// Block-cooperative DMA staging: LDS[p][slot] (PIXB=128) <- global dense
// NHWC-48 (96B/pixel).  LDS slot o of pixel p holds channel-octet
// m = o ^ (gx&7) (swizzle in LDS only -> conflict-free ds_read_b128).
// OOB pixels / pad octets <- zero page.  Caller must __syncthreads() after.
// 10x18 staged region, 1440 16-B items (+32 pad -> STAGE_K*64).
// ---------------------------------------------------------------------------
__device__ __forceinline__ void stage_swz(
    const char* __restrict__ srcimg, int oy0, int ox0,
    char* smem, const char* __restrict__ zp)
{
    int wv = threadIdx.x >> 6, lane = threadIdx.x & 63;
    for (int k = wv; k < STAGE_K; k += 4) {
        int w = k * 64 + lane;
        int px = w >> 3, o = w & 7;
        int yy = px / ITILE_W, xx = px - yy * ITILE_W;
        int gy = oy0 + yy - 1, gx = ox0 + xx - 1;
        int m = o ^ (gx & 7);
        const char* g = zp;
        if (px < NPIX && (unsigned)gy < 256u && (unsigned)gx < 256u && m < 6)
            g = srcimg + (size_t)((gy << 8) + gx) * GPIXB + m * 16;
        load_lds16(g, smem + k * 1024);
    }
}

// ---------------------------------------------------------------------------
// Core: 9-tap K=64 MFMA GEMM. M=48 (3 mtiles), N=16 px/row, 2 rows per wave.
// A-frags double-buffered across taps; B reads swizzle-indexed (2-way free).
// SWAP=true -> C[pix][oc] for float4 NCHW epilogue (conv2).
// ---------------------------------------------------------------------------
template <bool ACC, bool SWAP>
__device__ __forceinline__ void conv_core(
    const char* smem, const unsigned short* __restrict__ wfrag,
    int ox0, f32x4 acc[2][3])
{
    const int lane = threadIdx.x & 63;
    const int wv = threadIdx.x >> 6;
    const int n = lane & 15;
    const int quad = lane >> 4;
    const bf16x8* wp = (const bf16x8*)wfrag;

    if (!ACC) {
#pragma unroll
        for (int g = 0; g < 2; ++g)
#pragma unroll
            for (int mt = 0; mt < 3; ++mt)
                acc[g][mt] = (f32x4){0.f, 0.f, 0.f, 0.f};
    }

    // per-dx lane-dependent column offsets (kb0 and kb1 slots)
    int colb0[3], colb1[3];
#pragma unroll
    for (int dx = 0; dx < 3; ++dx) {
        int key = (ox0 - 1 + dx + n) & 7;
        colb0[dx] = (dx + n) * PIXB + ((quad ^ key) * 16);
        colb1[dx] = (dx + n) * PIXB + (((quad + 4) ^ key) * 16);
    }

    bf16x8 a[2][6];
#pragma unroll
    for (int mt = 0; mt < 3; ++mt) {
        a[0][mt]     = wp[(mt * 2 + 0) * 64 + lane];
        a[0][mt + 3] = wp[(mt * 2 + 1) * 64 + lane];
    }

#pragma unroll
    for (int tap = 0; tap < 9; ++tap) {
        const int cur = tap & 1;
        if (tap < 8) {
#pragma unroll
            for (int mt = 0; mt < 3; ++mt) {
                a[cur ^ 1][mt]     = wp[(((tap + 1) * 3 + mt) * 2 + 0) * 64 + lane];
                a[cur ^ 1][mt + 3] = wp[(((tap + 1) * 3 + mt) * 2 + 1) * 64 + lane];
            }
        }
        const int dy = tap / 3, dx = tap % 3;
#pragma unroll
        for (int g = 0; g < 2; ++g) {
            const int rowb = (wv * 2 + g + dy) * ROWB;
            bf16x8 b0 = *(const bf16x8*)(smem + rowb + colb0[dx]);
            bf16x8 b1 = *(const bf16x8*)(smem + rowb + colb1[dx]);
            if (SWAP) {
                acc[g][0] = __builtin_amdgcn_mfma_f32_16x16x32_bf16(b0, a[cur][0], acc[g][0], 0, 0, 0);
                acc[g][1] = __builtin_amdgcn_mfma_f32_16x16x32_bf16(b0, a[cur][1], acc[g][1], 0, 0, 0);
                acc[g][2] = __builtin_amdgcn_mfma_f32_16x16x32_bf16(b0, a[cur][2], acc[g][2], 0, 0, 0);
                acc[g][0] = __builtin_amdgcn_mfma_f32_16x16x32_bf16(b1, a[cur][3], acc[g][0], 0, 0, 0);
                acc[g][1] = __builtin_amdgcn_mfma_f32_16x16x32_bf16(b1, a[cur][4], acc[g][1], 0, 0, 0);
                acc[g][2] = __builtin_amdgcn_mfma_f32_16x16x32_bf16(b1, a[cur][5], acc[g][2], 0, 0, 0);
            } else {
                acc[g][0] = __builtin_amdgcn_mfma_f32_16x16x32_bf16(a[cur][0], b0, acc[g][0], 0, 0, 0);
                acc[g][1] = __builtin_amdgcn_mfma_f32_16x16x32_bf16(a[cur][1], b0, acc[g][1], 0, 0, 0);
                acc[g][2] = __builtin_amdgcn_mfma_f32_16x16x32_bf16(a[cur][2], b0, acc[g][2], 0, 0, 0);
                acc[g][0] = __builtin_amdgcn_mfma_f32_16x16x32_bf16(a[cur][3], b1, acc[g][0], 0, 0, 0);
                acc[g][1] = __builtin_amdgcn_mfma_f32_16x16x32_bf16(a[cur][4], b1, acc[g][1], 0, 0, 0);
                acc[g][2] = __builtin_amdgcn_mfma_f32_16x16x32_bf16(a[cur][5], b1, acc[g][2], 0, 0, 0);
            }
        }
    }
}

// dense NHWC-48 bf16 store of one conv result (oc channels of pixel col n)
__device__ __forceinline__ void store_pix(
    char* __restrict__ dstimg, int row, int col, int quad,
    const f32x4 v[3])
{
    size_t pb = (size_t)((row << 8) + col) * GPIXB;
#pragma unroll
    for (int mt = 0; mt < 3; ++mt) {
        u16x4 pk;
#pragma unroll
        for (int r = 0; r < 4; ++r) pk[r] = f2bf(v[mt][r]);
        *(u16x4*)(dstimg + pb + mt * 32 + quad * 8) = pk;
    }
}

// ---------------------------------------------------------------------------
// Kernel 4: Fx = conv3x3(xT, Wfx[b]) -> dense NHWC bf16, + fused GAP partials.
// ---------------------------------------------------------------------------
__global__ __launch_bounds__(256, 4) void fxconv_kernel(
    const unsigned short* __restrict__ xT, const unsigned short* __restrict__ wfxf,
    unsigned short* __restrict__ Fx, float* __restrict__ gapP,
    const float* __restrict__ zp)
{
    __shared__ __align__(16) char smem[LDSBYTES];
    int ox0 = blockIdx.x * TILE_W, oy0 = blockIdx.y * TILE_H, b = blockIdx.z;

    stage_swz((const char*)xT + (size_t)b * IMGB, oy0, ox0, smem, (const char*)zp);
    __syncthreads();

    f32x4 acc[2][3];
    conv_core<false, false>(smem, wfxf + (size_t)b * FRAG_ELEMS, ox0, acc);

    const int lane = threadIdx.x & 63;
    const int wv = threadIdx.x >> 6;
    const int n = lane & 15, quad = lane >> 4;
    char* dimg = (char*)Fx + (size_t)b * IMGB;

    float gsum[3][4];
#pragma unroll
    for (int mt = 0; mt < 3; ++mt)
#pragma unroll
        for (int r = 0; r < 4; ++r) gsum[mt][r] = 0.f;

#pragma unroll
    for (int g = 0; g < 2; ++g) {
        int row = oy0 + wv * 2 + g;
        store_pix(dimg, row, ox0 + n, quad, acc[g]);
#pragma unroll
        for (int mt = 0; mt < 3; ++mt)
#pragma unroll
            for (int r = 0; r < 4; ++r) gsum[mt][r] += acc[g][mt][r];
    }
    // reduce over the 16 pixel columns (n bits = lane bits 0..3)
#pragma unroll
    for (int mt = 0; mt < 3; ++mt)
#pragma unroll
        for (int r = 0; r < 4; ++r) {
            float v = gsum[mt][r];
            v += __shfl_xor(v, 1);
            v += __shfl_xor(v, 2);
            v += __shfl_xor(v, 4);
            v += __shfl_xor(v, 8);
            gsum[mt][r] = v;
        }

    // cross-wave reduce in LDS (smem free after conv_core by all waves)
    __syncthreads();
    float* smemf = (float*)smem;
    if (n == 0) {
#pragma unroll
        for (int mt = 0; mt < 3; ++mt)
#pragma unroll
            for (int r = 0; r < 4; ++r)
                smemf[wv * CH + mt * 16 + quad * 4 + r] = gsum[mt][r];
    }
    __syncthreads();
    int t = threadIdx.x;
    if (t < CH) {
        float v = smemf[t] + smemf[CH + t] + smemf[2 * CH + t] + smemf[3 * CH + t];
        int tile = blockIdx.y * 16 + blockIdx.x;   // [0, NTILES)
        gapP[((size_t)b * NTILES + tile) * CH + t] = v;
    }
}

// ---------------------------------------------------------------------------
// Kernel 5: routing. One block per image: reduce NTILES per-tile GAP
// partials (thread t owns tiles t and t+256), then linear + top-2 gate.
// ---------------------------------------------------------------------------
__global__ __launch_bounds__(256) void route_kernel(
    const float* __restrict__ gapP,
    const float* __restrict__ router_w,
    const float* __restrict__ router_b,
    float* __restrict__ gate, int* __restrict__ eidx)
{
    __shared__ float red4[4 * CH];
    __shared__ float scs[NEXP];
    int b = blockIdx.x, t = threadIdx.x;
    int lane = t & 63, wv = t >> 6;

    const float* s1 = gapP + ((size_t)b * NTILES + t) * CH;
    const float* s2 = s1 + 256 * CH;
    float s[CH];
#pragma unroll
    for (int c = 0; c < CH; c++) s[c] = s1[c] + s2[c];
#pragma unroll
    for (int c = 0; c < CH; c++) {
        float v = s[c];
        v += __shfl_xor(v, 1);
        v += __shfl_xor(v, 2);
        v += __shfl_xor(v, 4);
        v += __shfl_xor(v, 8);
        v += __shfl_xor(v, 16);
        v += __shfl_xor(v, 32);
        if (lane == 0) red4[wv * CH + c] = v;
    }
    __syncthreads();

    if (t < NEXP) {
        float sc = router_b[t];
        for (int c = 0; c < CH; c++) {
            float g = (red4[c] + red4[CH + c] + red4[2 * CH + c] + red4[3 * CH + c])
                      * (1.0f / HW);
            sc += g * router_w[t * CH + c];
        }
        scs[t] = sc;
    }
    __syncthreads();

    if (t == 0) {
        float v0 = -1e30f, v1 = -1e30f;
        int i0 = 0, i1 = 0;
        for (int e = 0; e < NEXP; e++) {
            float se = scs[e];
            if (se > v0) { v1 = v0; i1 = i0; v0 = se; i0 = e; }
            else if (se > v1) { v1 = se; i1 = e; }
        }
        float ex = expf(v1 - v0);
        float dn = 1.0f / (1.0f + ex);
        gate[b * 2 + 0] = dn;
        gate[b * 2 + 1] = ex * dn;
        eidx[b * 2 + 0] = i0;
        eidx[b * 2 + 1] = i1;
    }
}

// ---------------------------------------------------------------------------
// Kernel 6: w2s[b][slot] = gate[b][slot] * w2f[eidx[b][slot]]  (A-frag bf16).
// ---------------------------------------------------------------------------
__global__ __launch_bounds__(256) void scale_kernel(
    const unsigned short* __restrict__ w2f, const float* __restrict__ gate,
    const int* __restrict__ eidx, unsigned short* __restrict__ w2s)
{
    int b = blockIdx.x, s = blockIdx.y;
    int e = eidx[b * 2 + s];
    float g = gate[b * 2 + s];
    const unsigned short* src = w2f + (size_t)e * FRAG_ELEMS;
    unsigned short* dst = w2s + (size_t)(b * 2 + s) * FRAG_ELEMS;
    for (int i = threadIdx.x; i < FRAG_ELEMS; i += 256) {
        float v = __uint_as_float((unsigned)src[i] << 16);
        dst[i] = f2bf(v * g);
    }
}

// ---------------------------------------------------------------------------
// Kernel 7: both routed experts' conv1 from ONE staged Fx tile:
//   hmid_s = gelu(conv3x3(Fx, w1[e_s])), s = 0,1.
// ---------------------------------------------------------------------------
__global__ __launch_bounds__(256, 4) void conv1_both_kernel(
    const unsigned short* __restrict__ Fx, const unsigned short* __restrict__ w1f,
    const int* __restrict__ eidx, const float* __restrict__ zp,
    unsigned short* __restrict__ hmid0, unsigned short* __restrict__ hmid1)
{
    __shared__ __align__(16) char smem[LDSBYTES];
    int ox0 = blockIdx.x * TILE_W, oy0 = blockIdx.y * TILE_H, b = blockIdx.z;

    stage_swz((const char*)Fx + (size_t)b * IMGB, oy0, ox0, smem, (const char*)zp);
    __syncthreads();

    const int lane = threadIdx.x & 63;
    const int wv = threadIdx.x >> 6;
    const int n = lane & 15, quad = lane >> 4;

    f32x4 acc[2][3];
#pragma unroll
    for (int s = 0; s < 2; ++s) {
        int e = __builtin_amdgcn_readfirstlane(eidx[b * 2 + s]);
        conv_core<false, false>(smem, w1f + (size_t)e * FRAG_ELEMS, ox0, acc);
        char* dimg = (char*)(s ? hmid1 : hmid0) + (size_t)b * IMGB;
#pragma unroll
        for (int g = 0; g < 2; ++g) {
            int row = oy0 + wv * 2 + g;
            f32x4 h[3];
#pragma unroll
            for (int mt = 0; mt < 3; ++mt)
#pragma unroll
                for (int r = 0; r < 4; ++r) {
                    float a = acc[g][mt][r];
                    h[mt][r] = 0.5f * a * (1.0f + erff(a * 0.70710678118654752f));
                }
            store_pix(dimg, row, ox0 + n, quad, h);
        }
    }
}

// ---------------------------------------------------------------------------
// Kernel 8: out = x + conv3x3(hmid0, g0*w2[e0]) + conv3x3(hmid1, g1*w2[e1]).
// SWAPped MFMA -> C[pix][oc]: float4 NCHW residual/stores.  Pair-XCD
// swizzle keeps the two tiles sharing each 128-B out line on one XCD.
// ---------------------------------------------------------------------------
__global__ __launch_bounds__(256, 4) void conv2_both_kernel(
    const unsigned short* __restrict__ hmid0, const unsigned short* __restrict__ hmid1,
    const unsigned short* __restrict__ w2s, const float* __restrict__ zp,
    const float* __restrict__ x, float* __restrict__ out)
{
    __shared__ __align__(16) char smem[LDSBYTES];
    // d = rest*16 + half*8 + k8 -> bx = 2*k8+half, (by,b) = rest  (bijective)
    int d = blockIdx.x;
    int k8   = d & 7;
    int half = (d >> 3) & 1;
    int rest = d >> 4;             // [0, 256)
    int bx = k8 * 2 + half;        // [0, 16)
    int by = rest & 31;            // [0, 32)
    int b  = rest >> 5;            // [0, 8)
    int ox0 = bx * TILE_W, oy0 = by * TILE_H;

    const int lane = threadIdx.x & 63;
    const int wv = threadIdx.x >> 6;
    const int n = lane & 15, quad = lane >> 4;

    // residual prefetch: 6 float4/lane (pixels quad*4..+3 of oc nt*16+n)
    f32x4 xr[2][3];
#pragma unroll
    for (int g = 0; g < 2; ++g) {
        int row = oy0 + wv * 2 + g;
#pragma unroll
        for (int nt = 0; nt < 3; ++nt) {
            int oc = nt * 16 + n;
            size_t idx = (((size_t)b * CH + oc) << 16) + (row << 8) + ox0 + quad * 4;
            xr[g][nt] = *(const f32x4*)(x + idx);
        }
    }

    f32x4 acc[2][3];

    stage_swz((const char*)hmid0 + (size_t)b * IMGB, oy0, ox0, smem, (const char*)zp);
    __syncthreads();
    conv_core<false, true>(smem, w2s + (size_t)(b * 2 + 0) * FRAG_ELEMS, ox0, acc);
    __syncthreads();   // all waves done reading before re-stage

    stage_swz((const char*)hmid1 + (size_t)b * IMGB, oy0, ox0, smem, (const char*)zp);
    __syncthreads();
    conv_core<true, true>(smem, w2s + (size_t)(b * 2 + 1) * FRAG_ELEMS, ox0, acc);

#pragma unroll
    for (int g = 0; g < 2; ++g) {
        int row = oy0 + wv * 2 + g;
#pragma unroll
        for (int nt = 0; nt < 3; ++nt) {
            int oc = nt * 16 + n;
            size_t idx = (((size_t)b * CH + oc) << 16) + (row << 8) + ox0 + quad * 4;
            *(f32x4*)(out + idx) = xr[g][nt] + acc[g][nt];
        }
    }
}

// ---------------------------------------------------------------------------
extern "C" void kernel_launch(void* const* d_in, const int* in_sizes, int n_in,
                              void* d_out, int out_size, void* d_ws, size_t ws_size,
                              hipStream_t stream) {
    (void)in_sizes; (void)n_in; (void)out_size; (void)ws_size;
    const float* x          = (const float*)d_in[0];
    const float* P_hat      = (const float*)d_in[1];
    const float* proj_a_w   = (const float*)d_in[2];
    const float* proj_b_w   = (const float*)d_in[3];
    const float* dw_b_w     = (const float*)d_in[4];
    const float* fi_align_w = (const float*)d_in[5];
    const float* expert_w1  = (const float*)d_in[6];
    const float* expert_w2  = (const float*)d_in[7];
    const float* router_w   = (const float*)d_in[8];
    const float* router_b   = (const float*)d_in[9];
    float* out = (float*)d_out;

    // d_out doubles as scratch before the final conv2 pass overwrites it:
    //   [0, 50331648)          Fx (bf16 NHWC-48)
    //   [62914560, +1327104)   wfxf / w1f / w2f fragment tables
    //   [64241664, +786432)    gapP per-tile GAP partials (consumed by route)
    char* ob = (char*)d_out;
    unsigned short* Fx   = (unsigned short*)ob;
    unsigned short* wfxf = (unsigned short*)(ob + 62914560);
    unsigned short* w1f  = (unsigned short*)(ob + 62914560 + FRAG_BYTES * NEXP);
    unsigned short* w2f  = (unsigned short*)(ob + 62914560 + 2 * FRAG_BYTES * NEXP);
    float*          gapP = (float*)(ob + 64241664);

    // ws: xT (aliased by hmid1 after fxconv) | hmid0 | w2s | zpage | gate | eidx
    char* ws = (char*)d_ws;
    unsigned short* xT    = (unsigned short*)ws;               // 50331648 B
    unsigned short* hmid1 = (unsigned short*)ws;               // alias (xT dead)
    unsigned short* hmid0 = (unsigned short*)(ws + 50331648);  // 50331648 B
    unsigned short* w2s   = (unsigned short*)(ws + 100663296); // 884736 B
    float* zp   = (float*)(ws + 100663296 + 884736);           // 256 B
    float* gate = (float*)(ws + 100663296 + 884736 + 256 + 1536); // 64 B
    int*   eidx = (int*)(gate + BATCH * 2);                    // 64 B

    precompute_kernel<<<dim3(BATCH), 256, 0, stream>>>(
        P_hat, proj_a_w, proj_b_w, dw_b_w, fi_align_w, wfxf, zp);

    repack_kernel<<<dim3(NEXP, 2), 256, 0, stream>>>(
        expert_w1, expert_w2, w1f, w2f);

    transpose_kernel<<<dim3(BATCH * HW / 64), 256, 0, stream>>>(x, xT);

    fxconv_kernel<<<dim3(16, 32, BATCH), 256, 0, stream>>>(xT, wfxf, Fx, gapP, zp);

    route_kernel<<<dim3(BATCH), 256, 0, stream>>>(gapP, router_w, router_b, gate, eidx);

    scale_kernel<<<dim3(BATCH, 2), 256, 0, stream>>>(w2f, gate, eidx, w2s);

    conv1_both_kernel<<<dim3(16, 32, BATCH), 256, 0, stream>>>(
        Fx, w1f, eidx, zp, hmid0, hmid1);

    conv2_both_kernel<<<dim3(4096), 256, 0, stream>>>(
        hmid0, hmid1, w2s, zp, x, out);
}

// Round 8
// 471.400 us; speedup vs baseline: 2.2485x; 1.2080x over previous
//
#include <hip/hip_runtime.h>
#include <hip/hip_bf16.h>
#include <math.h>

#define BATCH 8
#define CH 48
#define HH 256
#define WW 256
#define NPROMPT 16
#define NEXP 8
#define NGRP 4
#define GDIM 12
#define HW (HH * WW)

// MFMA A-fragment tables: [tap(9)][mtile(3)][kblock(2)][lane(64)][j(8)] bf16
#define FRAG_ELEMS (9 * 3 * 2 * 64 * 8)   // 27648 elems = 55296 B per (image|expert)
#define FRAG_BYTES (FRAG_ELEMS * 2)

typedef short bf16x8 __attribute__((ext_vector_type(8)));   // 8 bf16 (4 VGPRs)
typedef float f32x4  __attribute__((ext_vector_type(4)));
typedef unsigned short u16x4 __attribute__((ext_vector_type(4)));

// 16x8 output tile, 23.5 KB staged LDS + 12.3 KB repack LDS -> 4 blocks/CU.
// R6/R7 lesson: conv_core's double-buffered A-frags (+48 VGPR) made the
// allocator spill under occupancy caps (R7: VGPR 64 < natural ~90 -> WRITE
// 368 MB vs 100 ideal).  R8: single-buffered frags (natural ~66) + LDS
// repack epilogue (full-line stores kill the 96 MB write-allocate FETCH).
#define TILE_W 16
#define TILE_H 8
#define ITILE_W 18                  // staged cols
#define ITILE_H 10                  // staged rows
#define NPIX (ITILE_W * ITILE_H)    // 180
#define PIXB 128                    // LDS bytes/pixel (8 slots x 16B, swizzled)
#define ROWB (ITILE_W * PIXB)       // 2304 B per staged row
#define STAGE_K 23                  // DMA chunks of 64 x 16B (1440 items + pad)
#define LDSBYTES (STAGE_K * 1024)   // 23552
#define RBUFB (TILE_H * TILE_W * GPIXB)   // 12288 B dense bf16 output tile
#define GPIXB 96                    // global NHWC-48 bf16 bytes/pixel
#define IMGB ((size_t)HW * GPIXB)   // 6291456 B per image
#define NTILES 512                  // (256/TILE_W)*(256/TILE_H)

__device__ __forceinline__ unsigned short f2bf(float f) {
    unsigned u = __float_as_uint(f);
    unsigned r = (u + 0x7FFFu + ((u >> 16) & 1u)) >> 16;   // RNE
    return (unsigned short)r;
}

// async global->LDS DMA, 16B per lane; lds dest = uniform base + lane*16
__device__ __forceinline__ void load_lds16(const void* g, void* l) {
    __builtin_amdgcn_global_load_lds(
        (const __attribute__((address_space(1))) unsigned int*)g,
        (__attribute__((address_space(3))) unsigned int*)l, 16, 0, 0);
}

// ---------------------------------------------------------------------------
// Kernel 1: fold branch-a + branch-b into per-image 3x3 weights in MFMA
// A-fragment layout. Also zero the DMA zero-page.
// ---------------------------------------------------------------------------
__global__ __launch_bounds__(256) void precompute_kernel(
    const float* __restrict__ P_hat,
    const float* __restrict__ proj_a_w,
    const float* __restrict__ proj_b_w,
    const float* __restrict__ dw_b_w,
    const float* __restrict__ fi_align_w,
    unsigned short* __restrict__ wfxf,
    float* __restrict__ zpage)
{
    int b = blockIdx.x;
    int tid = threadIdx.x;
    __shared__ float p_avg[CH];
    __shared__ float W_fi[NGRP * CH];
    __shared__ float W_a[CH * CH];

    if (tid < CH) {
        float s = 0.f;
        for (int n = 0; n < NPROMPT; n++)
            s += P_hat[(b * NPROMPT + n) * CH + tid];
        p_avg[tid] = s * (1.0f / NPROMPT);
    }
    if (b == 0 && tid < 64) zpage[tid] = 0.f;   // 256 B zero page
    __syncthreads();

    if (tid < NGRP * CH) {
        int g = tid / CH, k = tid % CH;
        float s = 0.f;
        for (int j = 0; j < GDIM; j++) {
            int c = g * GDIM + j;
            s += p_avg[c] * proj_a_w[c * CH + k];
        }
        W_fi[tid] = s;
    }
    __syncthreads();

    for (int e = tid; e < CH * CH; e += 256) {
        int o = e / CH, k = e % CH;
        float s = 0.f;
        for (int g = 0; g < NGRP; g++)
            s += fi_align_w[o * NGRP + g] * W_fi[g * CH + k];
        W_a[e] = s;
    }
    __syncthreads();

    for (int i = tid; i < FRAG_ELEMS; i += 256) {
        int j = i & 7;
        int lane = (i >> 3) & 63;
        int blk = i >> 9;            // (tap*3+mt)*2+kb
        int kb = blk & 1;
        int tmp = blk >> 1;
        int mt = tmp % 3, tap = tmp / 3;
        int oc = mt * 16 + (lane & 15);
        int cin = kb * 32 + (lane >> 4) * 8 + j;
        float v = 0.f;
        if (cin < CH) {
            v = dw_b_w[oc * 9 + tap] * proj_b_w[oc * CH + cin];
            if (tap == 4) v += W_a[oc * CH + cin];
        }
        wfxf[(size_t)b * FRAG_ELEMS + i] = f2bf(v);
    }
}

// ---------------------------------------------------------------------------
// Kernel 2: repack expert weights into MFMA A-fragment layout.
// ---------------------------------------------------------------------------
__global__ __launch_bounds__(256) void repack_kernel(
    const float* __restrict__ w1, const float* __restrict__ w2,
    unsigned short* __restrict__ w1f, unsigned short* __restrict__ w2f)
{
    int e = blockIdx.x;
    const float* src = blockIdx.y ? w2 : w1;
    unsigned short* dst = blockIdx.y ? w2f : w1f;
    for (int i = threadIdx.x; i < FRAG_ELEMS; i += 256) {
        int j = i & 7;
        int lane = (i >> 3) & 63;
        int blk = i >> 9;
        int kb = blk & 1;
        int tmp = blk >> 1;
        int mt = tmp % 3, tap = tmp / 3;
        int oc = mt * 16 + (lane & 15);
        int cin = kb * 32 + (lane >> 4) * 8 + j;
        float v = (cin < CH) ? src[(((size_t)e * CH + oc) * CH + cin) * 9 + tap] : 0.f;
        dst[(size_t)e * FRAG_ELEMS + i] = f2bf(v);
    }
}

// ---------------------------------------------------------------------------
// Kernel 3: transpose x NCHW fp32 -> dense NHWC-48 bf16 (96 B/pixel).
// ---------------------------------------------------------------------------
__global__ __launch_bounds__(256) void transpose_kernel(
    const float* __restrict__ x, unsigned short* __restrict__ xT)
{
    __shared__ float t[CH * 65];
    int pix0 = blockIdx.x * 64;
    int b = pix0 >> 16;
    int rem = pix0 & 65535;
    int tid = threadIdx.x;
    int px = tid & 63, c0 = tid >> 6;

    float v[12];
#pragma unroll
    for (int k = 0; k < 12; k++)
        v[k] = x[(((size_t)(b * CH + c0 + 4 * k)) << 16) + rem + px];
#pragma unroll
    for (int k = 0; k < 12; k++)
        t[(c0 + 4 * k) * 65 + px] = v[k];
    __syncthreads();

#pragma unroll
    for (int k = 0; k < 2; k++) {
        int w = tid + 256 * k;
        if (w < 384) {
            int p2 = w / 6, o = w % 6;
            bf16x8 pk;
#pragma unroll
            for (int j = 0; j < 8; j++)
                pk[j] = (short)f2bf(t[(o * 8 + j) * 65 + p2]);
            *(bf16x8*)((char*)xT + (size_t)pix0 * GPIXB + (size_t)w * 16) = pk;
        }
    }
}

// ---------------------------------------------------------------------------
// Block-cooperative DMA staging: LDS[p][slot] (PIXB=128) <- global dense
// NHWC-48 (96B/pixel).  LDS slot o of pixel p holds channel-octet
// m = o ^ (gx&7) (swizzle in LDS only -> conflict-free ds_read_b128).
// OOB pixels / pad octets <- zero page.  Caller must __syncthreads() after.
// ---------------------------------------------------------------------------
__device__ __forceinline__ void stage_swz(
    const char* __restrict__ srcimg, int oy0, int ox0,
    char* smem, const char* __restrict__ zp)
{
    int wv = threadIdx.x >> 6, lane = threadIdx.x & 63;
    for (int k = wv; k < STAGE_K; k += 4) {
        int w = k * 64 + lane;
        int px = w >> 3, o = w & 7;
        int yy = px / ITILE_W, xx = px - yy * ITILE_W;
        int gy = oy0 + yy - 1, gx = ox0 + xx - 1;
        int m = o ^ (gx & 7);
        const char* g = zp;
        if (px < NPIX && (unsigned)gy < 256u && (unsigned)gx < 256u && m < 6)
            g = srcimg + (size_t)((gy << 8) + gx) * GPIXB + m * 16;
        load_lds16(g, smem + k * 1024);
    }
}

// ---------------------------------------------------------------------------
// Core: 9-tap K=64 MFMA GEMM. M=48 (3 mtiles), N=16 px/row, 2 rows per wave.
// A-frags SINGLE-buffered (R8: the a[2][6] double buffer's +48 VGPR made the
// allocator spill under occupancy caps; compiler may re-pipeline within the
// 128-reg cap on its own).  B reads swizzle-indexed (2-way free).
// SWAP=true -> C[pix][oc] for float4 NCHW epilogue (conv2).
// ---------------------------------------------------------------------------
template <bool ACC, bool SWAP>
__device__ __forceinline__ void conv_core(
    const char* smem, const unsigned short* __restrict__ wfrag,
    int ox0, f32x4 acc[2][3])
{
    const int lane = threadIdx.x & 63;
    const int wv = threadIdx.x >> 6;
    const int n = lane & 15;
    const int quad = lane >> 4;
    const bf16x8* wp = (const bf16x8*)wfrag;

    if (!ACC) {
#pragma unroll
        for (int g = 0; g < 2; ++g)
#pragma unroll
            for (int mt = 0; mt < 3; ++mt)
                acc[g][mt] = (f32x4){0.f, 0.f, 0.f, 0.f};
    }

    // per-dx lane-dependent column offsets (kb0 and kb1 slots)
    int colb0[3], colb1[3];
#pragma unroll
    for (int dx = 0; dx < 3; ++dx) {
        int key = (ox0 - 1 + dx + n) & 7;
        colb0[dx] = (dx + n) * PIXB + ((quad ^ key) * 16);
        colb1[dx] = (dx + n) * PIXB + (((quad + 4) ^ key) * 16);
    }

#pragma unroll
    for (int tap = 0; tap < 9; ++tap) {
        bf16x8 a[6];
#pragma unroll
        for (int mt = 0; mt < 3; ++mt) {
            a[mt]     = wp[((tap * 3 + mt) * 2 + 0) * 64 + lane];
            a[mt + 3] = wp[((tap * 3 + mt) * 2 + 1) * 64 + lane];
        }
        const int dy = tap / 3, dx = tap % 3;
#pragma unroll
        for (int g = 0; g < 2; ++g) {
            const int rowb = (wv * 2 + g + dy) * ROWB;
            bf16x8 b0 = *(const bf16x8*)(smem + rowb + colb0[dx]);
            bf16x8 b1 = *(const bf16x8*)(smem + rowb + colb1[dx]);
            if (SWAP) {
                acc[g][0] = __builtin_amdgcn_mfma_f32_16x16x32_bf16(b0, a[0], acc[g][0], 0, 0, 0);
                acc[g][1] = __builtin_amdgcn_mfma_f32_16x16x32_bf16(b0, a[1], acc[g][1], 0, 0, 0);
                acc[g][2] = __builtin_amdgcn_mfma_f32_16x16x32_bf16(b0, a[2], acc[g][2], 0, 0, 0);
                acc[g][0] = __builtin_amdgcn_mfma_f32_16x16x32_bf16(b1, a[3], acc[g][0], 0, 0, 0);
                acc[g][1] = __builtin_amdgcn_mfma_f32_16x16x32_bf16(b1, a[4], acc[g][1], 0, 0, 0);
                acc[g][2] = __builtin_amdgcn_mfma_f32_16x16x32_bf16(b1, a[5], acc[g][2], 0, 0, 0);
            } else {
                acc[g][0] = __builtin_amdgcn_mfma_f32_16x16x32_bf16(a[0], b0, acc[g][0], 0, 0, 0);
                acc[g][1] = __builtin_amdgcn_mfma_f32_16x16x32_bf16(a[1], b0, acc[g][1], 0, 0, 0);
                acc[g][2] = __builtin_amdgcn_mfma_f32_16x16x32_bf16(a[2], b0, acc[g][2], 0, 0, 0);
                acc[g][0] = __builtin_amdgcn_mfma_f32_16x16x32_bf16(a[3], b1, acc[g][0], 0, 0, 0);
                acc[g][1] = __builtin_amdgcn_mfma_f32_16x16x32_bf16(a[4], b1, acc[g][1], 0, 0, 0);
                acc[g][2] = __builtin_amdgcn_mfma_f32_16x16x32_bf16(a[5], b1, acc[g][2], 0, 0, 0);
            }
        }
    }
}

// pack one conv result (acc layout: C[oc][pix]) into the dense bf16 repack
// buffer at (row prow, col n): 8-B chunk per (mt, quad)
__device__ __forceinline__ void pack_rbuf(
    char* rbuf, int prow, int n, int quad, const f32x4 v[3])
{
#pragma unroll
    for (int mt = 0; mt < 3; ++mt) {
        u16x4 pk;
#pragma unroll
        for (int r = 0; r < 4; ++r) pk[r] = f2bf(v[mt][r]);
        *(u16x4*)(rbuf + (prow * TILE_W + n) * GPIXB + mt * 32 + quad * 8) = pk;
    }
}

// stream the dense repack buffer to global: 768 chunks of 16 B, 3/thread,
// fully coalesced 128-B-aligned full-line writes (no write-allocate RMW).
__device__ __forceinline__ void stream_rbuf(
    const char* rbuf, char* __restrict__ dimg, int oy0, int ox0)
{
    int t = threadIdx.x;
#pragma unroll
    for (int i = 0; i < 3; ++i) {
        int c = t + i * 256;               // [0, 768)
        int row = c / 96;                  // 96 chunks per 1536-B row
        int off = (c - row * 96) * 16;
        bf16x8 v = *(const bf16x8*)(rbuf + c * 16);
        *(bf16x8*)(dimg + (size_t)(((oy0 + row) << 8) + ox0) * GPIXB + off) = v;
    }
}

// ---------------------------------------------------------------------------
// Kernel 4: Fx = conv3x3(xT, Wfx[b]) -> dense NHWC bf16, + fused GAP partials.
// ---------------------------------------------------------------------------
__global__ __launch_bounds__(256, 4) void fxconv_kernel(
    const unsigned short* __restrict__ xT, const unsigned short* __restrict__ wfxf,
    unsigned short* __restrict__ Fx, float* __restrict__ gapP,
    const float* __restrict__ zp)
{
    __shared__ __align__(16) char smem[LDSBYTES];
    __shared__ __align__(16) char rbuf[RBUFB];
    int ox0 = blockIdx.x * TILE_W, oy0 = blockIdx.y * TILE_H, b = blockIdx.z;

    stage_swz((const char*)xT + (size_t)b * IMGB, oy0, ox0, smem, (const char*)zp);
    __syncthreads();

    f32x4 acc[2][3];
    conv_core<false, false>(smem, wfxf + (size_t)b * FRAG_ELEMS, ox0, acc);

    const int lane = threadIdx.x & 63;
    const int wv = threadIdx.x >> 6;
    const int n = lane & 15, quad = lane >> 4;

    float gsum[3][4];
#pragma unroll
    for (int mt = 0; mt < 3; ++mt)
#pragma unroll
        for (int r = 0; r < 4; ++r) gsum[mt][r] = 0.f;

#pragma unroll
    for (int g = 0; g < 2; ++g) {
        pack_rbuf(rbuf, wv * 2 + g, n, quad, acc[g]);
#pragma unroll
        for (int mt = 0; mt < 3; ++mt)
#pragma unroll
            for (int r = 0; r < 4; ++r) gsum[mt][r] += acc[g][mt][r];
    }
    // reduce over the 16 pixel columns (n bits = lane bits 0..3)
#pragma unroll
    for (int mt = 0; mt < 3; ++mt)
#pragma unroll
        for (int r = 0; r < 4; ++r) {
            float v = gsum[mt][r];
            v += __shfl_xor(v, 1);
            v += __shfl_xor(v, 2);
            v += __shfl_xor(v, 4);
            v += __shfl_xor(v, 8);
            gsum[mt][r] = v;
        }

    __syncthreads();   // rbuf complete; smem (staged) now reusable

    stream_rbuf(rbuf, (char*)Fx + (size_t)b * IMGB, oy0, ox0);

    float* smemf = (float*)smem;
    if (n == 0) {
#pragma unroll
        for (int mt = 0; mt < 3; ++mt)
#pragma unroll
            for (int r = 0; r < 4; ++r)
                smemf[wv * CH + mt * 16 + quad * 4 + r] = gsum[mt][r];
    }
    __syncthreads();
    int t = threadIdx.x;
    if (t < CH) {
        float v = smemf[t] + smemf[CH + t] + smemf[2 * CH + t] + smemf[3 * CH + t];
        int tile = blockIdx.y * 16 + blockIdx.x;   // [0, NTILES)
        gapP[((size_t)b * NTILES + tile) * CH + t] = v;
    }
}

// ---------------------------------------------------------------------------
// Kernel 5: routing. One block per image: reduce NTILES per-tile GAP
// partials (thread t owns tiles t and t+256), then linear + top-2 gate.
// ---------------------------------------------------------------------------
__global__ __launch_bounds__(256) void route_kernel(
    const float* __restrict__ gapP,
    const float* __restrict__ router_w,
    const float* __restrict__ router_b,
    float* __restrict__ gate, int* __restrict__ eidx)
{
    __shared__ float red4[4 * CH];
    __shared__ float scs[NEXP];
    int b = blockIdx.x, t = threadIdx.x;
    int lane = t & 63, wv = t >> 6;

    const float* s1 = gapP + ((size_t)b * NTILES + t) * CH;
    const float* s2 = s1 + 256 * CH;
    float s[CH];
#pragma unroll
    for (int c = 0; c < CH; c++) s[c] = s1[c] + s2[c];
#pragma unroll
    for (int c = 0; c < CH; c++) {
        float v = s[c];
        v += __shfl_xor(v, 1);
        v += __shfl_xor(v, 2);
        v += __shfl_xor(v, 4);
        v += __shfl_xor(v, 8);
        v += __shfl_xor(v, 16);
        v += __shfl_xor(v, 32);
        if (lane == 0) red4[wv * CH + c] = v;
    }
    __syncthreads();

    if (t < NEXP) {
        float sc = router_b[t];
        for (int c = 0; c < CH; c++) {
            float g = (red4[c] + red4[CH + c] + red4[2 * CH + c] + red4[3 * CH + c])
                      * (1.0f / HW);
            sc += g * router_w[t * CH + c];
        }
        scs[t] = sc;
    }
    __syncthreads();

    if (t == 0) {
        float v0 = -1e30f, v1 = -1e30f;
        int i0 = 0, i1 = 0;
        for (int e = 0; e < NEXP; e++) {
            float se = scs[e];
            if (se > v0) { v1 = v0; i1 = i0; v0 = se; i0 = e; }
            else if (se > v1) { v1 = se; i1 = e; }
        }
        float ex = expf(v1 - v0);
        float dn = 1.0f / (1.0f + ex);
        gate[b * 2 + 0] = dn;
        gate[b * 2 + 1] = ex * dn;
        eidx[b * 2 + 0] = i0;
        eidx[b * 2 + 1] = i1;
    }
}

// ---------------------------------------------------------------------------
// Kernel 6: w2s[b][slot] = gate[b][slot] * w2f[eidx[b][slot]]  (A-frag bf16).
// ---------------------------------------------------------------------------
__global__ __launch_bounds__(256) void scale_kernel(
    const unsigned short* __restrict__ w2f, const float* __restrict__ gate,
    const int* __restrict__ eidx, unsigned short* __restrict__ w2s)
{
    int b = blockIdx.x, s = blockIdx.y;
    int e = eidx[b * 2 + s];
    float g = gate[b * 2 + s];
    const unsigned short* src = w2f + (size_t)e * FRAG_ELEMS;
    unsigned short* dst = w2s + (size_t)(b * 2 + s) * FRAG_ELEMS;
    for (int i = threadIdx.x; i < FRAG_ELEMS; i += 256) {
        float v = __uint_as_float((unsigned)src[i] << 16);
        dst[i] = f2bf(v * g);
    }
}

// ---------------------------------------------------------------------------
// Kernel 7: both routed experts' conv1 from ONE staged Fx tile:
//   hmid_s = gelu(conv3x3(Fx, w1[e_s])), s = 0,1.
// LDS-repacked epilogue: full-line hmid stores (no write-allocate).
// ---------------------------------------------------------------------------
__global__ __launch_bounds__(256, 4) void conv1_both_kernel(
    const unsigned short* __restrict__ Fx, const unsigned short* __restrict__ w1f,
    const int* __restrict__ eidx, const float* __restrict__ zp,
    unsigned short* __restrict__ hmid0, unsigned short* __restrict__ hmid1)
{
    __shared__ __align__(16) char smem[LDSBYTES];
    __shared__ __align__(16) char rbuf[RBUFB];
    int ox0 = blockIdx.x * TILE_W, oy0 = blockIdx.y * TILE_H, b = blockIdx.z;

    stage_swz((const char*)Fx + (size_t)b * IMGB, oy0, ox0, smem, (const char*)zp);
    __syncthreads();

    const int lane = threadIdx.x & 63;
    const int wv = threadIdx.x >> 6;
    const int n = lane & 15, quad = lane >> 4;

    f32x4 acc[2][3];
#pragma unroll
    for (int s = 0; s < 2; ++s) {
        int e = __builtin_amdgcn_readfirstlane(eidx[b * 2 + s]);
        conv_core<false, false>(smem, w1f + (size_t)e * FRAG_ELEMS, ox0, acc);
#pragma unroll
        for (int g = 0; g < 2; ++g) {
            f32x4 h[3];
#pragma unroll
            for (int mt = 0; mt < 3; ++mt)
#pragma unroll
                for (int r = 0; r < 4; ++r) {
                    float a = acc[g][mt][r];
                    h[mt][r] = 0.5f * a * (1.0f + erff(a * 0.70710678118654752f));
                }
            pack_rbuf(rbuf, wv * 2 + g, n, quad, h);
        }
        __syncthreads();   // rbuf complete (smem untouched for 2nd expert)
        stream_rbuf(rbuf, (char*)(s ? hmid1 : hmid0) + (size_t)b * IMGB, oy0, ox0);
        __syncthreads();   // rbuf reads done before next expert overwrites
    }
}

// ---------------------------------------------------------------------------
// Kernel 8: out = x + conv3x3(hmid0, g0*w2[e0]) + conv3x3(hmid1, g1*w2[e1]).
// SWAPped MFMA -> C[pix][oc]: float4 NCHW residual/stores (x loaded in the
// epilogue: avoids 24 long-lived VGPRs across both conv phases).  Pair-XCD
// swizzle keeps the two tiles sharing each 128-B out line on one XCD.
// ---------------------------------------------------------------------------
__global__ __launch_bounds__(256, 4) void conv2_both_kernel(
    const unsigned short* __restrict__ hmid0, const unsigned short* __restrict__ hmid1,
    const unsigned short* __restrict__ w2s, const float* __restrict__ zp,
    const float* __restrict__ x, float* __restrict__ out)
{
    __shared__ __align__(16) char smem[LDSBYTES];
    // d = rest*16 + half*8 + k8 -> bx = 2*k8+half, (by,b) = rest  (bijective)
    int d = blockIdx.x;
    int k8   = d & 7;
    int half = (d >> 3) & 1;
    int rest = d >> 4;             // [0, 256)
    int bx = k8 * 2 + half;        // [0, 16)
    int by = rest & 31;            // [0, 32)
    int b  = rest >> 5;            // [0, 8)
    int ox0 = bx * TILE_W, oy0 = by * TILE_H;

    const int lane = threadIdx.x & 63;
    const int wv = threadIdx.x >> 6;
    const int n = lane & 15, quad = lane >> 4;

    f32x4 acc[2][3];

    stage_swz((const char*)hmid0 + (size_t)b * IMGB, oy0, ox0, smem, (const char*)zp);
    __syncthreads();
    conv_core<false, true>(smem, w2s + (size_t)(b * 2 + 0) * FRAG_ELEMS, ox0, acc);
    __syncthreads();   // all waves done reading before re-stage

    stage_swz((const char*)hmid1 + (size_t)b * IMGB, oy0, ox0, smem, (const char*)zp);
    __syncthreads();
    conv_core<true, true>(smem, w2s + (size_t)(b * 2 + 1) * FRAG_ELEMS, ox0, acc);

#pragma unroll
    for (int g = 0; g < 2; ++g) {
        int row = oy0 + wv * 2 + g;
#pragma unroll
        for (int nt = 0; nt < 3; ++nt) {
            int oc = nt * 16 + n;
            size_t idx = (((size_t)b * CH + oc) << 16) + (row << 8) + ox0 + quad * 4;
            f32x4 xr = *(const f32x4*)(x + idx);
            *(f32x4*)(out + idx) = xr + acc[g][nt];
        }
    }
}

// ---------------------------------------------------------------------------
extern "C" void kernel_launch(void* const* d_in, const int* in_sizes, int n_in,
                              void* d_out, int out_size, void* d_ws, size_t ws_size,
                              hipStream_t stream) {
    (void)in_sizes; (void)n_in; (void)out_size; (void)ws_size;
    const float* x          = (const float*)d_in[0];
    const float* P_hat      = (const float*)d_in[1];
    const float* proj_a_w   = (const float*)d_in[2];
    const float* proj_b_w   = (const float*)d_in[3];
    const float* dw_b_w     = (const float*)d_in[4];
    const float* fi_align_w = (const float*)d_in[5];
    const float* expert_w1  = (const float*)d_in[6];
    const float* expert_w2  = (const float*)d_in[7];
    const float* router_w   = (const float*)d_in[8];
    const float* router_b   = (const float*)d_in[9];
    float* out = (float*)d_out;

    // d_out doubles as scratch before the final conv2 pass overwrites it:
    //   [0, 50331648)          Fx (bf16 NHWC-48)
    //   [62914560, +1327104)   wfxf / w1f / w2f fragment tables
    //   [64241664, +786432)    gapP per-tile GAP partials (consumed by route)
    char* ob = (char*)d_out;
    unsigned short* Fx   = (unsigned short*)ob;
    unsigned short* wfxf = (unsigned short*)(ob + 62914560);
    unsigned short* w1f  = (unsigned short*)(ob + 62914560 + FRAG_BYTES * NEXP);
    unsigned short* w2f  = (unsigned short*)(ob + 62914560 + 2 * FRAG_BYTES * NEXP);
    float*          gapP = (float*)(ob + 64241664);

    // ws: xT (aliased by hmid1 after fxconv) | hmid0 | w2s | zpage | gate | eidx
    char* ws = (char*)d_ws;
    unsigned short* xT    = (unsigned short*)ws;               // 50331648 B
    unsigned short* hmid1 = (unsigned short*)ws;               // alias (xT dead)
    unsigned short* hmid0 = (unsigned short*)(ws + 50331648);  // 50331648 B
    unsigned short* w2s   = (unsigned short*)(ws + 100663296); // 884736 B
    float* zp   = (float*)(ws + 100663296 + 884736);           // 256 B
    float* gate = (float*)(ws + 100663296 + 884736 + 256 + 1536); // 64 B
    int*   eidx = (int*)(gate + BATCH * 2);                    // 64 B

    precompute_kernel<<<dim3(BATCH), 256, 0, stream>>>(
        P_hat, proj_a_w, proj_b_w, dw_b_w, fi_align_w, wfxf, zp);

    repack_kernel<<<dim3(NEXP, 2), 256, 0, stream>>>(
        expert_w1, expert_w2, w1f, w2f);

    transpose_kernel<<<dim3(BATCH * HW / 64), 256, 0, stream>>>(x, xT);

    fxconv_kernel<<<dim3(16, 32, BATCH), 256, 0, stream>>>(xT, wfxf, Fx, gapP, zp);

    route_kernel<<<dim3(BATCH), 256, 0, stream>>>(gapP, router_w, router_b, gate, eidx);

    scale_kernel<<<dim3(BATCH, 2), 256, 0, stream>>>(w2f, gate, eidx, w2s);

    conv1_both_kernel<<<dim3(16, 32, BATCH), 256, 0, stream>>>(
        Fx, w1f, eidx, zp, hmid0, hmid1);

    conv2_both_kernel<<<dim3(4096), 256, 0, stream>>>(
        hmid0, hmid1, w2s, zp, x, out);
}